// Round 5
// baseline (20.125 us; speedup 1.0000x reference)
//
#include <hip/hip_runtime.h>

#define V 10
#define L 45            // V*(V-1)/2
#define NCOEF 14
#define NSAMP 65536
#define BS 32           // samples per block
#define NTHR 128        // 2 waves
#define LAMP 46         // padded lam row stride

typedef float v4f __attribute__((ext_vector_type(4)));

// packed (i<<4)|j for pair l (tril_indices(V, k=-1) row-major order)
__constant__ unsigned char c_ij[L] = {
    0x10,
    0x20,0x21,
    0x30,0x31,0x32,
    0x40,0x41,0x42,0x43,
    0x50,0x51,0x52,0x53,0x54,
    0x60,0x61,0x62,0x63,0x64,0x65,
    0x70,0x71,0x72,0x73,0x74,0x75,0x76,
    0x80,0x81,0x82,0x83,0x84,0x85,0x86,0x87,
    0x90,0x91,0x92,0x93,0x94,0x95,0x96,0x97,0x98
};

__global__ __launch_bounds__(NTHR, 8) void decor_fused(
    const float* __restrict__ x, const float* __restrict__ log_d,
    const float* __restrict__ params,
    float* __restrict__ out, float* __restrict__ Mout, float* __restrict__ logd_out,
    float* __restrict__ scal)
{
    __shared__ float ps[NCOEF * L];          // 2.52 KB
    __shared__ float xs[BS * V];             // 1.28 KB
    __shared__ float lam[BS * LAMP];         // 5.89 KB
    __shared__ unsigned char ij[48];

    const int tid = threadIdx.x;
    const int n0  = blockIdx.x * BS;
    float* __restrict__ Mb = Mout + (size_t)n0 * V * V;

    // ---- issue loads first: params + x -> LDS ----
    for (int idx = tid; idx < NCOEF * L; idx += NTHR)
        ps[idx] = params[idx];
    const v4f* x4 = (const v4f*)(x + (size_t)n0 * V);
    for (int idx = tid; idx < BS * V / 4; idx += NTHR)
        ((v4f*)xs)[idx] = x4[idx];
    if (tid < L) ij[tid] = c_ij[tid];

    // ---- constant part of M (j>=i): pure stores, hide under load latency ----
    for (int idx = tid; idx < BS * V * V; idx += NTHR) {
        int e = idx % (V * V);
        int i = (e * 205) >> 11;       // e/10 for e<100
        int j = e - 10 * i;
        if (j >= i) Mb[idx] = (j == i) ? 1.0f : 0.0f;
    }

    // ---- log_d passthrough (float4) ----
    const v4f* ld4  = (const v4f*)(log_d + (size_t)n0 * V);
    v4f*       ldo4 = (v4f*)(logd_out + (size_t)n0 * V);
    for (int idx = tid; idx < BS * V / 4; idx += NTHR)
        ldo4[idx] = ld4[idx];

    __syncthreads();

    // ---- lambdas: compute, write LDS copy + scatter straight to global M ----
    // uniform knots, spacing d = 10/11; u = (x+5)/d + 3
    const float inv_d = 1.1f;
    const float c16   = 1.0f / 6.0f;
    for (int idx = tid; idx < BS * L; idx += NTHR) {
        int nl = idx / L;
        int l  = idx - nl * L;
        int pij = ij[l];
        int i = pij >> 4, j = pij & 15;
        float xv = xs[nl * V + j];
        xv = fminf(fmaxf(xv, -5.0f), 5.0f);
        float u  = (xv + 5.0f) * inv_d + 3.0f;
        int   ii = (int)floorf(u);
        ii = max(3, min(ii, 14));          // ref indicator: x=+5 lands in [t14,t15)
        float f  = u - (float)ii;
        float omf = 1.0f - f;
        float f2 = f * f, f3 = f2 * f;
        float N0 = omf * omf * omf * c16;
        float N1 = (3.0f * f3 - 6.0f * f2 + 4.0f) * c16;
        float N2 = (-3.0f * f3 + 3.0f * f2 + 3.0f * f + 1.0f) * c16;
        float N3 = f3 * c16;               // == 0 when ii==14
        int k0 = ii - 3;
        int k3 = min(k0 + 3, NCOEF - 1);   // B_14 dropped by ref; N3==0 there
        float lv =
              N0 * ps[(k0    ) * L + l]
            + N1 * ps[(k0 + 1) * L + l]
            + N2 * ps[(k0 + 2) * L + l]
            + N3 * ps[(k3    ) * L + l];
        lam[nl * LAMP + l] = lv;
        Mb[nl * V * V + i * V + j] = lv;   // lower-tri: disjoint from const loop
    }

    // ---- ridge scalars: wave 0 of block 0 (ps ready after barrier above... 
    //      compute here, overlapping other blocks' traffic) ----
    __syncthreads();

    // ---- out = M @ x (strict-lower + identity), direct coalesced stores ----
    for (int idx = tid; idx < BS * V; idx += NTHR) {
        int nl = idx / V;
        int i  = idx - nl * V;
        float acc = xs[idx];
        const float* lr = &lam[nl * LAMP + (i * (i - 1)) / 2];
        for (int j = 0; j < i; ++j)
            acc += lr[j] * xs[nl * V + j];
        out[(size_t)n0 * V + idx] = acc;
    }

    if (blockIdx.x == 0 && tid < 64) {
        float s_par = 0.f, s_fir = 0.f, s_sec = 0.f;
        for (int idx = tid; idx < NCOEF * L; idx += 64) {
            int k = idx / L;
            float p0 = ps[idx];
            s_par += p0 * p0;
            if (k + 1 < NCOEF) {
                float p1 = ps[idx + L];
                float d1 = p1 - p0;
                s_fir += d1 * d1;
                if (k + 2 < NCOEF) {
                    float p2 = ps[idx + 2 * L];
                    float d2 = p2 - 2.f * p1 + p0;
                    s_sec += d2 * d2;
                }
            }
        }
        for (int off = 32; off; off >>= 1) {
            s_sec += __shfl_down(s_sec, off);
            s_fir += __shfl_down(s_fir, off);
            s_par += __shfl_down(s_par, off);
        }
        if (tid == 0) { scal[0] = s_sec; scal[1] = s_fir; scal[2] = s_par; }
    }
}

extern "C" void kernel_launch(void* const* d_in, const int* in_sizes, int n_in,
                              void* d_out, int out_size, void* d_ws, size_t ws_size,
                              hipStream_t stream) {
    const float* x      = (const float*)d_in[0];
    const float* log_d  = (const float*)d_in[1];
    const float* params = (const float*)d_in[2];

    float* out      = (float*)d_out;                       // [N, V]
    float* M        = out + (size_t)NSAMP * V;             // [N, V, V]
    float* logd_out = M + (size_t)NSAMP * V * V;           // [N, V]
    float* scal     = logd_out + (size_t)NSAMP * V;        // sec, fir, par

    decor_fused<<<NSAMP / BS, NTHR, 0, stream>>>(x, log_d, params, out, M, logd_out, scal);
}